// Round 1
// baseline (1256.136 us; speedup 1.0000x reference)
//
#include <hip/hip_runtime.h>
#include <cfloat>

// VQ-VAE vector quantizer, fp32.
// N=262144 rows x D=100 dims, K=512 codes.
// out[0 .. N*D-1]   = quantized (gathered codebook rows)   [= quantized_st fwd]
// out[N*D]          = mean((q-x)^2)                        [quantization_loss]
// out[N*D+1]        = 0.25 * mean((q-x)^2)                 [commitment_loss]
//
// ws layout (floats): ws[0] = global sum((q-x)^2) accumulator
//                     ws[64 .. 64+511] = e2[k] = sum_j emb[k][j]^2

#define N_ROWS (64 * 64 * 64)
#define D 100
#define KCODES 512

// ---- init: zero loss accumulator, precompute per-code squared norms ----
__global__ __launch_bounds__(512) void vq_init(const float* __restrict__ emb,
                                               float* __restrict__ ws) {
    int k = threadIdx.x;            // one thread per code, block = 512
    if (k == 0) ws[0] = 0.0f;       // ws is re-poisoned to 0xAA every call
    const float* e = emb + k * D;
    float s = 0.0f;
#pragma unroll
    for (int j = 0; j < D; ++j) s = fmaf(e[j], e[j], s);
    ws[64 + k] = s;
}

// ---- main: per-lane row, codebook streamed through scalar (SGPR) loads ----
__global__ __launch_bounds__(256) void vq_main(const float* __restrict__ x,
                                               const float* __restrict__ emb,
                                               float* __restrict__ ws,
                                               float* __restrict__ out) {
    const float* __restrict__ e2 = ws + 64;
    const long row = (long)blockIdx.x * 256 + threadIdx.x;   // grid covers N exactly

    // load this lane's row into registers (25 x float4 = 100 VGPRs)
    const float4* __restrict__ xr = (const float4*)(x + row * (long)D);
    float4 xv[D / 4];
#pragma unroll
    for (int j = 0; j < D / 4; ++j) xv[j] = xr[j];

    float smin = FLT_MAX;
    int kmin = 0;
    // s_k = e2[k] - 2 * <x, e_k>.  k and j are wave-uniform -> emb/e2 reads
    // become s_load into SGPRs; v_fma_f32 takes the SGPR operand directly.
#pragma unroll 2
    for (int k = 0; k < KCODES; ++k) {
        const float4* __restrict__ ek = (const float4*)(emb + k * D);
        float a0 = 0.0f, a1 = 0.0f, a2 = 0.0f, a3 = 0.0f;  // 4 indep chains
#pragma unroll
        for (int j = 0; j < D / 4; ++j) {
            float4 e = ek[j];
            a0 = fmaf(e.x, xv[j].x, a0);
            a1 = fmaf(e.y, xv[j].y, a1);
            a2 = fmaf(e.z, xv[j].z, a2);
            a3 = fmaf(e.w, xv[j].w, a3);
        }
        float s = fmaf(-2.0f, (a0 + a1) + (a2 + a3), e2[k]);
        if (s < smin) { smin = s; kmin = k; }   // strict < keeps first index (argmin tie rule)
    }

    // gather winning code (divergent vector loads, served from L2: table is 205 KB),
    // write quantized output, accumulate local squared error
    const float4* __restrict__ eq = (const float4*)(emb + kmin * D);
    float4* __restrict__ outr = (float4*)(out + row * (long)D);
    float lsum = 0.0f;
#pragma unroll
    for (int j = 0; j < D / 4; ++j) {
        float4 q = eq[j];
        outr[j] = q;
        float d0 = q.x - xv[j].x;
        float d1 = q.y - xv[j].y;
        float d2 = q.z - xv[j].z;
        float d3 = q.w - xv[j].w;
        lsum = fmaf(d0, d0, lsum);
        lsum = fmaf(d1, d1, lsum);
        lsum = fmaf(d2, d2, lsum);
        lsum = fmaf(d3, d3, lsum);
    }

    // wave(64) shuffle reduce -> cross-wave LDS reduce -> one atomic per block
#pragma unroll
    for (int off = 32; off > 0; off >>= 1) lsum += __shfl_down(lsum, off);
    __shared__ float wsum[4];
    if ((threadIdx.x & 63) == 0) wsum[threadIdx.x >> 6] = lsum;
    __syncthreads();
    if (threadIdx.x == 0)
        atomicAdd(ws, wsum[0] + wsum[1] + wsum[2] + wsum[3]);
}

// ---- finalize: write the two loss scalars ----
__global__ void vq_final(const float* __restrict__ ws, float* __restrict__ out) {
    float mse = ws[0] / (float)(N_ROWS * D);
    out[(long)N_ROWS * D]     = mse;          // quantization_loss
    out[(long)N_ROWS * D + 1] = 0.25f * mse;  // commitment_loss
}

extern "C" void kernel_launch(void* const* d_in, const int* in_sizes, int n_in,
                              void* d_out, int out_size, void* d_ws, size_t ws_size,
                              hipStream_t stream) {
    const float* x   = (const float*)d_in[0];   // inputs    [64,64,64,100] fp32
    const float* emb = (const float*)d_in[1];   // embedding [512,100]      fp32
    float* out = (float*)d_out;
    float* ws  = (float*)d_ws;

    vq_init<<<1, 512, 0, stream>>>(emb, ws);
    vq_main<<<N_ROWS / 256, 256, 0, stream>>>(x, emb, ws, out);
    vq_final<<<1, 1, 0, stream>>>(ws, out);
}

// Round 2
// 710.534 us; speedup vs baseline: 1.7679x; 1.7679x over previous
//
#include <hip/hip_runtime.h>
#include <cfloat>

// VQ-VAE vector quantizer, fp32.  N=262144 rows x D=100 dims, K=512 codes.
// out[0 .. N*D-1] = quantized;  out[N*D] = mse;  out[N*D+1] = 0.25*mse.
//
// R2: codebook streamed through LDS tiles (wave-uniform broadcast reads),
// 2 rows per thread to amortize the codebook reads over 2x the FMAs.
// ws layout (floats): ws[0] = global sum((q-x)^2); ws[64..64+511] = e2[k].

#define N_ROWS (64 * 64 * 64)
#define D 100
#define KCODES 512
#define TK 64                    // codes per LDS tile (64*100*4 = 25.6 KB)
#define NTILES (KCODES / TK)     // 8
#define ROWS_PER_BLOCK 512       // 256 threads x 2 rows

// ---- init: zero loss accumulator, precompute per-code squared norms ----
__global__ __launch_bounds__(512) void vq_init(const float* __restrict__ emb,
                                               float* __restrict__ ws) {
    int k = threadIdx.x;
    if (k == 0) ws[0] = 0.0f;
    const float* e = emb + k * D;
    float s = 0.0f;
#pragma unroll
    for (int j = 0; j < D; ++j) s = fmaf(e[j], e[j], s);
    ws[64 + k] = s;
}

// ---- main ----
__global__ __launch_bounds__(256, 2) void vq_main(const float* __restrict__ x,
                                                  const float* __restrict__ emb,
                                                  float* __restrict__ ws,
                                                  float* __restrict__ out) {
    __shared__ float se[TK * D];    // 25600 B codebook tile
    __shared__ float se2[TK];       // tile of squared norms

    const float* __restrict__ e2 = ws + 64;
    const int tid = threadIdx.x;
    const long r0 = (long)blockIdx.x * ROWS_PER_BLOCK + tid;
    const long r1 = r0 + 256;

    // both rows register-resident: 2 x 25 float4 = 200 VGPRs
    const float4* __restrict__ xr0 = (const float4*)(x + r0 * (long)D);
    const float4* __restrict__ xr1 = (const float4*)(x + r1 * (long)D);
    float4 xv0[D / 4], xv1[D / 4];
#pragma unroll
    for (int j = 0; j < D / 4; ++j) { xv0[j] = xr0[j]; xv1[j] = xr1[j]; }

    float smin0 = FLT_MAX, smin1 = FLT_MAX;
    int kmin0 = 0, kmin1 = 0;

    for (int t = 0; t < NTILES; ++t) {
        // stage tile: 1600 float4, coalesced
        const float4* __restrict__ src = (const float4*)(emb + t * TK * D);
        for (int i = tid; i < TK * D / 4; i += 256)
            ((float4*)se)[i] = src[i];
        if (tid < TK) se2[tid] = e2[t * TK + tid];
        __syncthreads();

#pragma unroll 2
        for (int k = 0; k < TK; ++k) {
            const float4* __restrict__ ek = (const float4*)(se + k * D);
            float a0 = 0, a1 = 0, a2 = 0, a3 = 0;   // row0 chains
            float b0 = 0, b1 = 0, b2 = 0, b3 = 0;   // row1 chains
#pragma unroll
            for (int j = 0; j < D / 4; ++j) {
                float4 e = ek[j];
                a0 = fmaf(e.x, xv0[j].x, a0);
                a1 = fmaf(e.y, xv0[j].y, a1);
                a2 = fmaf(e.z, xv0[j].z, a2);
                a3 = fmaf(e.w, xv0[j].w, a3);
                b0 = fmaf(e.x, xv1[j].x, b0);
                b1 = fmaf(e.y, xv1[j].y, b1);
                b2 = fmaf(e.z, xv1[j].z, b2);
                b3 = fmaf(e.w, xv1[j].w, b3);
            }
            float c = se2[k];
            float s0 = fmaf(-2.0f, (a0 + a1) + (a2 + a3), c);
            float s1 = fmaf(-2.0f, (b0 + b1) + (b2 + b3), c);
            int kk = t * TK + k;
            if (s0 < smin0) { smin0 = s0; kmin0 = kk; }  // strict <: first-index tie rule
            if (s1 < smin1) { smin1 = s1; kmin1 = kk; }
        }
        __syncthreads();
    }

    // epilogue: gather winners (L2-resident table), write, accumulate sq error
    float lsum = 0.0f;
    {
        const float4* __restrict__ eq = (const float4*)(emb + kmin0 * D);
        float4* __restrict__ outr = (float4*)(out + r0 * (long)D);
#pragma unroll
        for (int j = 0; j < D / 4; ++j) {
            float4 q = eq[j];
            outr[j] = q;
            float d0 = q.x - xv0[j].x, d1 = q.y - xv0[j].y;
            float d2 = q.z - xv0[j].z, d3 = q.w - xv0[j].w;
            lsum = fmaf(d0, d0, lsum); lsum = fmaf(d1, d1, lsum);
            lsum = fmaf(d2, d2, lsum); lsum = fmaf(d3, d3, lsum);
        }
    }
    {
        const float4* __restrict__ eq = (const float4*)(emb + kmin1 * D);
        float4* __restrict__ outr = (float4*)(out + r1 * (long)D);
#pragma unroll
        for (int j = 0; j < D / 4; ++j) {
            float4 q = eq[j];
            outr[j] = q;
            float d0 = q.x - xv1[j].x, d1 = q.y - xv1[j].y;
            float d2 = q.z - xv1[j].z, d3 = q.w - xv1[j].w;
            lsum = fmaf(d0, d0, lsum); lsum = fmaf(d1, d1, lsum);
            lsum = fmaf(d2, d2, lsum); lsum = fmaf(d3, d3, lsum);
        }
    }

    // wave shuffle reduce -> cross-wave LDS -> one atomic per block
#pragma unroll
    for (int off = 32; off > 0; off >>= 1) lsum += __shfl_down(lsum, off);
    __shared__ float wsum[4];
    if ((tid & 63) == 0) wsum[tid >> 6] = lsum;
    __syncthreads();
    if (tid == 0)
        atomicAdd(ws, wsum[0] + wsum[1] + wsum[2] + wsum[3]);
}

// ---- finalize ----
__global__ void vq_final(const float* __restrict__ ws, float* __restrict__ out) {
    float mse = ws[0] / (float)(N_ROWS * D);
    out[(long)N_ROWS * D]     = mse;
    out[(long)N_ROWS * D + 1] = 0.25f * mse;
}

extern "C" void kernel_launch(void* const* d_in, const int* in_sizes, int n_in,
                              void* d_out, int out_size, void* d_ws, size_t ws_size,
                              hipStream_t stream) {
    const float* x   = (const float*)d_in[0];
    const float* emb = (const float*)d_in[1];
    float* out = (float*)d_out;
    float* ws  = (float*)d_ws;

    vq_init<<<1, 512, 0, stream>>>(emb, ws);
    vq_main<<<N_ROWS / ROWS_PER_BLOCK, 256, 0, stream>>>(x, emb, ws, out);
    vq_final<<<1, 1, 0, stream>>>(ws, out);
}

// Round 3
// 278.993 us; speedup vs baseline: 4.5024x; 2.5468x over previous
//
#include <hip/hip_runtime.h>
#include <cfloat>
#include <stdint.h>

// VQ-VAE vector quantizer.  N=262144 rows x D=100, K=512 codes.
// out[0..N*D-1] = quantized (fp32-exact gather); out[N*D]=mse; out[N*D+1]=0.25*mse.
//
// R3: bf16 MFMA 16x16x32. S = X·E^T fused with per-row argmin.
//  - A (x rows) lives as MFMA fragments in VGPRs (4 M-tiles/wave = 64 rows/wave).
//  - Codebook pre-converted ONCE (vq_init) to bf16 in exact B-fragment order in ws;
//    main loop loads B frags straight from L2 (132 KB resident). No LDS in hot loop.
//  - mse from sum_rows(||x||^2_fp32 + s_min),  s = e2 - 2<x,e>  =>  ||x-e||^2.
//
// ws layout: ws_f[0] = loss accumulator; ws_f[16..16+512) = e2[k];
//            bytes [4096 .. 4096+131072) = bf16 codebook, B-fragment order:
//            [chunk(16)][s(4)][code_in_chunk(32)][quad(4)][j(8)]  (k = s*32+quad*8+j, zero-pad k>=100)

#define N_ROWS (64 * 64 * 64)
#define D 100
#define KCODES 512
#define CB_OFF 4096
#define E2_OFF 16
#define WS_NEEDED ((size_t)(CB_OFF + KCODES * 128 * 2))

typedef __attribute__((ext_vector_type(8))) short short8;
typedef __attribute__((ext_vector_type(4))) float f32x4;

__device__ __forceinline__ unsigned short f2bf(float f) {
    union { float f; unsigned u; } v; v.f = f;
    unsigned r = v.u + 0x7FFF + ((v.u >> 16) & 1);   // RNE
    return (unsigned short)(r >> 16);
}

// ---- init: zero accumulator, e2[k], and bf16 codebook in B-fragment order ----
__global__ __launch_bounds__(256) void vq_init(const float* __restrict__ emb,
                                               float* __restrict__ ws) {
    int code = blockIdx.x * 256 + threadIdx.x;      // grid 2x256 = 512 codes
    if (code == 0) ws[0] = 0.0f;
    const float* e = emb + code * D;
    float s2 = 0.0f;
    for (int k = 0; k < D; ++k) s2 = fmaf(e[k], e[k], s2);
    ws[E2_OFF + code] = s2;

    unsigned short* cb = (unsigned short*)((char*)ws + CB_OFF);
    int chunk = code >> 5, ci = code & 31;
    for (int s = 0; s < 4; ++s)
        for (int q = 0; q < 4; ++q) {
            short8 v;
#pragma unroll
            for (int j = 0; j < 8; ++j) {
                int k = s * 32 + q * 8 + j;
                float f = (k < D) ? e[k] : 0.0f;
                v[j] = (short)f2bf(f);
            }
            *(short8*)(cb + ((((chunk * 4 + s) * 32 + ci) * 4 + q) * 8)) = v;
        }
}

// ---- main: 256 thr = 4 waves; wave = 64 rows (4 M-tiles); 16 chunks of 32 codes ----
__global__ __launch_bounds__(256, 2) void vq_main(const float* __restrict__ x,
                                                  const float* __restrict__ emb,
                                                  float* __restrict__ ws,
                                                  float* __restrict__ out) {
    const int tid  = threadIdx.x;
    const int wave = tid >> 6;
    const int lane = tid & 63;
    const int quad = lane >> 4;    // A/B: k = quad*8+j ; C: row = quad*4+reg
    const int lr   = lane & 15;    // A: row ; B: col ; C: col

    const long rowbase = (long)blockIdx.x * 256 + wave * 64;

    // ---- load A fragments (bf16) + fp32 row norms ----
    short8 A[4][4];        // [m-tile][k-step]
    float  xnorm[4];       // ||x_row||^2 for row = m*16+lr (valid in all lanes)
#pragma unroll
    for (int m = 0; m < 4; ++m) {
        const float* xr = x + (rowbase + m * 16 + lr) * D;
        float nrm = 0.0f;
#pragma unroll
        for (int s = 0; s < 4; ++s) {
            float4 f0 = {0, 0, 0, 0}, f1 = {0, 0, 0, 0};
            if (s < 3) {
                f0 = *(const float4*)(xr + s * 32 + quad * 8);
                f1 = *(const float4*)(xr + s * 32 + quad * 8 + 4);
            } else if (quad == 0) {
                f0 = *(const float4*)(xr + 96);   // k=96..99 (row tail); rest is pad
            }
            nrm = fmaf(f0.x, f0.x, nrm); nrm = fmaf(f0.y, f0.y, nrm);
            nrm = fmaf(f0.z, f0.z, nrm); nrm = fmaf(f0.w, f0.w, nrm);
            nrm = fmaf(f1.x, f1.x, nrm); nrm = fmaf(f1.y, f1.y, nrm);
            nrm = fmaf(f1.z, f1.z, nrm); nrm = fmaf(f1.w, f1.w, nrm);
            short8 a;
            a[0] = (short)f2bf(f0.x); a[1] = (short)f2bf(f0.y);
            a[2] = (short)f2bf(f0.z); a[3] = (short)f2bf(f0.w);
            a[4] = (short)f2bf(f1.x); a[5] = (short)f2bf(f1.y);
            a[6] = (short)f2bf(f1.z); a[7] = (short)f2bf(f1.w);
            A[m][s] = a;
        }
        nrm += __shfl_xor(nrm, 16);   // sum k-slices across quads
        nrm += __shfl_xor(nrm, 32);
        xnorm[m] = nrm;
    }

    const unsigned short* cb = (const unsigned short*)((const char*)ws + CB_OFF);
    const float* e2g = ws + E2_OFF;

    float    runmin[4][4];
    unsigned runidx[4][4];
#pragma unroll
    for (int m = 0; m < 4; ++m)
#pragma unroll
        for (int r = 0; r < 4; ++r) { runmin[m][r] = FLT_MAX; runidx[m][r] = 0; }

#pragma unroll 2
    for (int chunk = 0; chunk < 16; ++chunk) {
        short8 B[2][4];    // [n-tile][k-step], straight from L2 in fragment order
#pragma unroll
        for (int t = 0; t < 2; ++t)
#pragma unroll
            for (int s = 0; s < 4; ++s)
                B[t][s] = *(const short8*)(cb +
                    ((((chunk * 4 + s) * 32 + t * 16 + lr) * 4 + quad) * 8));
        float e2v0 = e2g[chunk * 32 + lr];
        float e2v1 = e2g[chunk * 32 + 16 + lr];

        f32x4 acc[4][2];
#pragma unroll
        for (int m = 0; m < 4; ++m)
#pragma unroll
            for (int t = 0; t < 2; ++t) acc[m][t] = (f32x4){0.f, 0.f, 0.f, 0.f};

#pragma unroll
        for (int s = 0; s < 4; ++s)
#pragma unroll
            for (int m = 0; m < 4; ++m)
#pragma unroll
                for (int t = 0; t < 2; ++t)
                    acc[m][t] = __builtin_amdgcn_mfma_f32_16x16x32_bf16(
                        A[m][s], B[t][s], acc[m][t], 0, 0, 0);

        // fold: score = e2 - 2*<x,e>;  C layout: row=quad*4+r, col=lr
#pragma unroll
        for (int m = 0; m < 4; ++m)
#pragma unroll
            for (int t = 0; t < 2; ++t) {
                float e2v = t ? e2v1 : e2v0;
                unsigned code = chunk * 32 + t * 16 + lr;
#pragma unroll
                for (int r = 0; r < 4; ++r) {
                    float sc = fmaf(-2.0f, acc[m][t][r], e2v);
                    if (sc < runmin[m][r]) { runmin[m][r] = sc; runidx[m][r] = code; }
                }
            }
    }

    // ---- per-row argmin across the 16 columns held by the quad's lanes ----
    __shared__ int   rowidx[256];
    __shared__ float wsum[4];
    float lsum = 0.0f;
#pragma unroll
    for (int m = 0; m < 4; ++m)
#pragma unroll
        for (int r = 0; r < 4; ++r) {
            float    s = runmin[m][r];
            unsigned i = runidx[m][r];
#pragma unroll
            for (int off = 8; off >= 1; off >>= 1) {   // xor 8,4,2,1: stays in quad
                float    os = __shfl_xor(s, off);
                unsigned oi = (unsigned)__shfl_xor((int)i, off);
                if (os < s || (os == s && oi < i)) { s = os; i = oi; }
            }
            if (lr == quad * 4 + r) {                  // one lane per (quad,r)
                lsum += xnorm[m] + s;                  // ||x||^2 + (e2-2<x,e>) = ||x-e||^2
                rowidx[wave * 64 + m * 16 + quad * 4 + r] = (int)i;
            }
        }
#pragma unroll
    for (int off = 32; off >= 1; off >>= 1) lsum += __shfl_xor(lsum, off);
    if (lane == 0) wsum[wave] = lsum;
    __syncthreads();
    if (tid == 0) atomicAdd(ws, wsum[0] + wsum[1] + wsum[2] + wsum[3]);

    // ---- gather winners (fp32-exact) and write output rows ----
    const int idx = rowidx[tid];
    const float4* __restrict__ eq = (const float4*)(emb + idx * D);
    float4* __restrict__ o = (float4*)(out + ((long)blockIdx.x * 256 + tid) * D);
#pragma unroll
    for (int j = 0; j < 25; ++j) o[j] = eq[j];
}

// ---- finalize ----
__global__ void vq_final(const float* __restrict__ ws, float* __restrict__ out) {
    float mse = ws[0] / (float)((long)N_ROWS * D);
    out[(long)N_ROWS * D]     = mse;
    out[(long)N_ROWS * D + 1] = 0.25f * mse;
}

// ======================= fallback (R2 path) if ws too small =======================
__global__ __launch_bounds__(512) void vq_init_fb(const float* __restrict__ emb,
                                                  float* __restrict__ ws) {
    int k = threadIdx.x;
    if (k == 0) ws[0] = 0.0f;
    const float* e = emb + k * D;
    float s = 0.0f;
#pragma unroll
    for (int j = 0; j < D; ++j) s = fmaf(e[j], e[j], s);
    ws[64 + k] = s;
}

#define TK 64
__global__ __launch_bounds__(256, 2) void vq_main_fb(const float* __restrict__ x,
                                                     const float* __restrict__ emb,
                                                     float* __restrict__ ws,
                                                     float* __restrict__ out) {
    __shared__ float se[TK * D];
    __shared__ float se2[TK];
    const float* __restrict__ e2 = ws + 64;
    const int tid = threadIdx.x;
    const long r0 = (long)blockIdx.x * 512 + tid;
    const long r1 = r0 + 256;
    const float4* __restrict__ xr0 = (const float4*)(x + r0 * (long)D);
    const float4* __restrict__ xr1 = (const float4*)(x + r1 * (long)D);
    float4 xv0[D / 4], xv1[D / 4];
#pragma unroll
    for (int j = 0; j < D / 4; ++j) { xv0[j] = xr0[j]; xv1[j] = xr1[j]; }
    float smin0 = FLT_MAX, smin1 = FLT_MAX;
    int kmin0 = 0, kmin1 = 0;
    for (int t = 0; t < KCODES / TK; ++t) {
        const float4* __restrict__ src = (const float4*)(emb + t * TK * D);
        for (int i = tid; i < TK * D / 4; i += 256) ((float4*)se)[i] = src[i];
        if (tid < TK) se2[tid] = e2[t * TK + tid];
        __syncthreads();
#pragma unroll 2
        for (int k = 0; k < TK; ++k) {
            const float4* __restrict__ ek = (const float4*)(se + k * D);
            float a0 = 0, a1 = 0, a2 = 0, a3 = 0, b0 = 0, b1 = 0, b2 = 0, b3 = 0;
#pragma unroll
            for (int j = 0; j < D / 4; ++j) {
                float4 e = ek[j];
                a0 = fmaf(e.x, xv0[j].x, a0); a1 = fmaf(e.y, xv0[j].y, a1);
                a2 = fmaf(e.z, xv0[j].z, a2); a3 = fmaf(e.w, xv0[j].w, a3);
                b0 = fmaf(e.x, xv1[j].x, b0); b1 = fmaf(e.y, xv1[j].y, b1);
                b2 = fmaf(e.z, xv1[j].z, b2); b3 = fmaf(e.w, xv1[j].w, b3);
            }
            float c = se2[k];
            float s0 = fmaf(-2.0f, (a0 + a1) + (a2 + a3), c);
            float s1 = fmaf(-2.0f, (b0 + b1) + (b2 + b3), c);
            int kk = t * TK + k;
            if (s0 < smin0) { smin0 = s0; kmin0 = kk; }
            if (s1 < smin1) { smin1 = s1; kmin1 = kk; }
        }
        __syncthreads();
    }
    float lsum = 0.0f;
    {
        const float4* __restrict__ eq = (const float4*)(emb + kmin0 * D);
        float4* __restrict__ outr = (float4*)(out + r0 * (long)D);
#pragma unroll
        for (int j = 0; j < D / 4; ++j) {
            float4 q = eq[j]; outr[j] = q;
            float d0 = q.x - xv0[j].x, d1 = q.y - xv0[j].y;
            float d2 = q.z - xv0[j].z, d3 = q.w - xv0[j].w;
            lsum = fmaf(d0, d0, lsum); lsum = fmaf(d1, d1, lsum);
            lsum = fmaf(d2, d2, lsum); lsum = fmaf(d3, d3, lsum);
        }
    }
    {
        const float4* __restrict__ eq = (const float4*)(emb + kmin1 * D);
        float4* __restrict__ outr = (float4*)(out + r1 * (long)D);
#pragma unroll
        for (int j = 0; j < D / 4; ++j) {
            float4 q = eq[j]; outr[j] = q;
            float d0 = q.x - xv1[j].x, d1 = q.y - xv1[j].y;
            float d2 = q.z - xv1[j].z, d3 = q.w - xv1[j].w;
            lsum = fmaf(d0, d0, lsum); lsum = fmaf(d1, d1, lsum);
            lsum = fmaf(d2, d2, lsum); lsum = fmaf(d3, d3, lsum);
        }
    }
#pragma unroll
    for (int off = 32; off > 0; off >>= 1) lsum += __shfl_down(lsum, off);
    __shared__ float wsum[4];
    if ((tid & 63) == 0) wsum[tid >> 6] = lsum;
    __syncthreads();
    if (tid == 0) atomicAdd(ws, wsum[0] + wsum[1] + wsum[2] + wsum[3]);
}

extern "C" void kernel_launch(void* const* d_in, const int* in_sizes, int n_in,
                              void* d_out, int out_size, void* d_ws, size_t ws_size,
                              hipStream_t stream) {
    const float* x   = (const float*)d_in[0];
    const float* emb = (const float*)d_in[1];
    float* out = (float*)d_out;
    float* ws  = (float*)d_ws;

    if (ws_size >= WS_NEEDED) {
        vq_init<<<2, 256, 0, stream>>>(emb, ws);
        vq_main<<<N_ROWS / 256, 256, 0, stream>>>(x, emb, ws, out);
    } else {
        vq_init_fb<<<1, 512, 0, stream>>>(emb, ws);
        vq_main_fb<<<N_ROWS / 512, 256, 0, stream>>>(x, emb, ws, out);
    }
    vq_final<<<1, 1, 0, stream>>>(ws, out);
}